// Round 12
// baseline (2112.428 us; speedup 1.0000x reference)
//
#include <hip/hip_runtime.h>

// ---------------------------------------------------------------------------
// Encoder: x=emb[enc]; xp = x@Wx + b_in; reset-after GRU over T=256 steps;
// out = h_last[:, 200:700].  All float inputs fp32; output fp32.
//
// Persistent weight-stationary GRU, per-WAVE dataflow sync (R11 base, 2062us):
//   R12: publish flag via agent-scope fetch_add RMW (executes AT the
//        coherence point -> immediately visible to agent-scope pollers),
//        replacing the relaxed agent store whose L2->IF$ propagation is
//        suspected lazy (R6..R11: three poll-side overhauls moved the step
//        only 9.15->8.06us; compute is ~2k cyc of a 19.4k cyc step, so ~6us
//        is publish->observe). No RMW contention: each per-wave flag is
//        RMW'd once per step by its owner; polls stay plain relaxed agent
//        loads (mechanism proven in R6).
//   - Per-wave dataflow: consumer wave rt polls the 44 same-rt producer-wave
//     flags lane-parallel; no __syncthreads in the 256-step loop.
//     Race-freedom: P's phase-overwrite at step t+1 is gated on flag_C>=t+2,
//     published only after C's step-t reads (data dep through MFMA->epilogue).
//   - R10a emb prefetch, R10b v_exp epilogue, ring-buffer A prefetch depth 8.
//   - 176 blocks; swizzle g=bx&7, s=bx>>3; HW_REG_XCC_ID check selects
//     fast (relaxed flags + l1_inv) or slow (release/acquire) per group.
//   - h fp32 in regs; exchanged as bf16 hi/lo pair through Wh buffer.
//   - d_ws: [8] grid barrier, [16..191] xcc, [256..1279] wave flags.
// ---------------------------------------------------------------------------

typedef unsigned short ushort_t;
typedef __bf16 bf16x8 __attribute__((ext_vector_type(8)));
typedef unsigned short ushort8 __attribute__((ext_vector_type(8)));
typedef float floatx4 __attribute__((ext_vector_type(4)));

#define NGRP   8
#define NSLC   22
#define NBLK   176
#define SB     840   // LDS row stride (bf16): 832 + 8 pad
#define HP     704
#define AH_ROW 1408  // hi[704] | lo[704]
#define PHASE  (256 * AH_ROW)
#define FLAGW(gg, ss, ww) (256 + (gg) * 128 + (ss) * 4 + (ww))

__device__ __forceinline__ float bf2f(ushort_t u) {
    unsigned v = ((unsigned)u) << 16; float f; __builtin_memcpy(&f, &v, 4); return f;
}
__device__ __forceinline__ ushort_t f2bf(float f) {
    unsigned u; __builtin_memcpy(&u, &f, 4);
    unsigned r = u + 0x7fff + ((u >> 16) & 1);
    return (ushort_t)(r >> 16);
}
__device__ __forceinline__ bf16x8 ld8(const ushort_t* p) {
    return __builtin_bit_cast(bf16x8, *(const ushort8*)p);
}
__device__ __forceinline__ bf16x8 cvt8(floatx4 a, floatx4 b) {
    ushort8 r = {f2bf(a.x), f2bf(a.y), f2bf(a.z), f2bf(a.w),
                 f2bf(b.x), f2bf(b.y), f2bf(b.z), f2bf(b.w)};
    return __builtin_bit_cast(bf16x8, r);
}
__device__ __forceinline__ void l1_inv() {
    asm volatile("buffer_inv sc0" ::: "memory");
}
__device__ __forceinline__ void wave_drain() {   // wave-local store drain
    asm volatile("s_waitcnt vmcnt(0)" ::: "memory");
}
__device__ __forceinline__ float fast_rcp(float x) {
    float r; asm("v_rcp_f32 %0, %1" : "=v"(r) : "v"(x)); return r;
}
__device__ __forceinline__ float fast_exp(float x) {
    float r; asm("v_exp_f32 %0, %1" : "=v"(r) : "v"(x * 1.44269504f)); return r;
}

__global__ void init_cnt(int* cnt) {
    for (int i = threadIdx.x; i < 1280; i += 1024) cnt[i] = 0;
}

__global__ __launch_bounds__(256, 1) void gru_main(
    const int* __restrict__ enc, const float* __restrict__ emb,
    const float* __restrict__ Wx, float* whf,
    const float* __restrict__ lab, const float* __restrict__ W1,
    const float* __restrict__ b1, const float* __restrict__ bias,
    float* __restrict__ out, int* cnt) {

    extern __shared__ ushort_t Bs[];   // [96][SB] bf16
    const int bx = blockIdx.x;
    const int g = bx & 7, s = bx >> 3;
    const int tid = threadIdx.x;
    const int wave = tid >> 6, lane = tid & 63;
    const int rt = wave >> 1, ct = wave & 1;
    const int q = lane >> 4, m = lane & 15;

    // ---- one-time staging: Bs[p][k] = bf16(W[k][col(p)]), p = gate*32+c ----
    for (int idx = tid; idx < 96 * 832; idx += 256) {
        int p = idx % 96, k = idx / 96;
        int c = s * 32 + (p & 31);
        ushort_t v = 0;
        if (c < 700) {
            int col = (p >> 5) * 700 + c;
            if (k < 100) v = f2bf(Wx[k * 2100 + col]);
            else if (k >= 128 && k < 828) v = f2bf(whf[(k - 128) * 2100 + col]);
        }
        Bs[p * SB + k] = v;
    }
    __syncthreads();   // all Wh reads of this block retired

    // ---- publish xcc id, then grid barrier (agent scope, one-time) ---------
    if (tid == 0) {
        int xcc;
        asm("s_getreg_b32 %0, hwreg(HW_REG_XCC_ID)" : "=s"(xcc));
        __hip_atomic_store(cnt + 16 + bx, xcc, __ATOMIC_RELAXED, __HIP_MEMORY_SCOPE_AGENT);
        __hip_atomic_fetch_add(cnt + 8, 1, __ATOMIC_ACQ_REL, __HIP_MEMORY_SCOPE_AGENT);
        while (__hip_atomic_load(cnt + 8, __ATOMIC_ACQUIRE, __HIP_MEMORY_SCOPE_AGENT) < NBLK)
            __builtin_amdgcn_s_sleep(1);
    }
    __syncthreads();

    // ---- fast iff all 22 peers share an XCD --------------------------------
    bool fast = true;
    {
        int myx = __hip_atomic_load(cnt + 16 + bx, __ATOMIC_RELAXED, __HIP_MEMORY_SCOPE_AGENT);
        for (int s2 = 0; s2 < NSLC; ++s2) {
            int px = __hip_atomic_load(cnt + 16 + g + 8 * s2, __ATOMIC_RELAXED, __HIP_MEMORY_SCOPE_AGENT);
            fast = fast && (px == myx);
        }
    }

    const int j = s * 32 + ct * 16 + m;
    float bzc = 0.f, brc = 0.f, b0h = 0.f, b1h = 0.f;
    if (j < 700) {
        bzc = bias[j] + bias[2100 + j];
        brc = bias[700 + j] + bias[2800 + j];
        b0h = bias[1400 + j];
        b1h = bias[3500 + j];
    }
    const int rowa = g * 32 + rt * 16 + m;

    ushort_t* Ah = (ushort_t*)whf;
    int* myflag = cnt + FLAGW(g, s, wave);
    // consumer wave rt needs flags (s2, rt*2+ct') for s2=0..21, ct'=0..1
    int* pollp = (lane < 44)
               ? (cnt + FLAGW(g, lane >> 1, rt * 2 + (lane & 1)))
               : (int*)nullptr;

    // ---- h0; publish hi/lo to phase 0 (per-wave) ---------------------------
    float hown[4];
#pragma unroll
    for (int i = 0; i < 4; i++) {
        int rowc = g * 32 + rt * 16 + q * 4 + i;
        float v = 0.f;
        if (j < 200) v = lab[rowc] * W1[j] + b1[j];
        hown[i] = v;
        ushort_t hi = f2bf(v);
        Ah[rowc * AH_ROW + j] = hi;
        Ah[rowc * AH_ROW + HP + j] = f2bf(v - bf2f(hi));
    }
    if (fast) {
        wave_drain();
        if (lane == 0)
            __hip_atomic_fetch_add(myflag, 1, __ATOMIC_RELAXED, __HIP_MEMORY_SCOPE_AGENT);
    } else {
        if (lane == 0)
            __hip_atomic_store(myflag, 1, __ATOMIC_RELEASE, __HIP_MEMORY_SCOPE_AGENT);
        else
            __threadfence();
    }

    const ushort_t* bsz = Bs + (ct * 16 + m) * SB;
    const ushort_t* bsr = Bs + (32 + ct * 16 + m) * SB;
    const ushort_t* bsh = Bs + (64 + ct * 16 + m) * SB;

    // ---- initial x prefetch for t=0 ----------------------------------------
    floatx4 pf[6]; floatx4 pft;
    {
        int tok = enc[rowa * 256 + 0];
        const float* ep = emb + tok * 100;
#pragma unroll
        for (int kt = 0; kt < 3; ++kt) {
            pf[kt * 2]     = *(const floatx4*)(ep + kt * 32 + q * 8);
            pf[kt * 2 + 1] = *(const floatx4*)(ep + kt * 32 + q * 8 + 4);
        }
        pft = *(const floatx4*)(ep + 96);
    }

    for (int t = 0; t < 256; ++t) {
        const ushort_t* Asrc = Ah + (t & 1) * PHASE;
        ushort_t* Adst = Ah + ((t + 1) & 1) * PHASE;
        floatx4 accz = {0,0,0,0}, accr = {0,0,0,0}, accrh = {0,0,0,0}, accxh = {0,0,0,0};

        // x-part from prefetched registers (off the critical chain)
#pragma unroll
        for (int kt = 0; kt < 3; ++kt) {
            bf16x8 a = cvt8(pf[kt * 2], pf[kt * 2 + 1]);
            int kb = kt * 32 + q * 8;
            accz  = __builtin_amdgcn_mfma_f32_16x16x32_bf16(a, ld8(bsz + kb), accz, 0, 0, 0);
            accr  = __builtin_amdgcn_mfma_f32_16x16x32_bf16(a, ld8(bsr + kb), accr, 0, 0, 0);
            accxh = __builtin_amdgcn_mfma_f32_16x16x32_bf16(a, ld8(bsh + kb), accxh, 0, 0, 0);
        }
        {
            ushort8 t8 = {0, 0, 0, 0, 0, 0, 0, 0};
            if (q == 0) {
                t8[0] = f2bf(pft.x); t8[1] = f2bf(pft.y);
                t8[2] = f2bf(pft.z); t8[3] = f2bf(pft.w);
            }
            bf16x8 a = __builtin_bit_cast(bf16x8, t8);
            int kb = 96 + q * 8;
            accz  = __builtin_amdgcn_mfma_f32_16x16x32_bf16(a, ld8(bsz + kb), accz, 0, 0, 0);
            accr  = __builtin_amdgcn_mfma_f32_16x16x32_bf16(a, ld8(bsr + kb), accr, 0, 0, 0);
            accxh = __builtin_amdgcn_mfma_f32_16x16x32_bf16(a, ld8(bsh + kb), accxh, 0, 0, 0);
        }
        // prefetch x for t+1 (in flight during the wait)
        {
            int tn = (t < 255) ? t + 1 : 255;
            int tok = enc[rowa * 256 + tn];
            const float* ep = emb + tok * 100;
#pragma unroll
            for (int kt = 0; kt < 3; ++kt) {
                pf[kt * 2]     = *(const floatx4*)(ep + kt * 32 + q * 8);
                pf[kt * 2 + 1] = *(const floatx4*)(ep + kt * 32 + q * 8 + 4);
            }
            pft = *(const floatx4*)(ep + 96);
        }

        // wait (per-wave, lane-parallel over the 44 relevant producer waves)
        if (lane < 44) {
            if (fast) {
                int spin = 0;
                while (__hip_atomic_load(pollp, __ATOMIC_RELAXED, __HIP_MEMORY_SCOPE_AGENT) < t + 1) {
                    if (++spin > 64) __builtin_amdgcn_s_sleep(1);
                }
            } else {
                while (__hip_atomic_load(pollp, __ATOMIC_ACQUIRE, __HIP_MEMORY_SCOPE_AGENT) < t + 1)
                    __builtin_amdgcn_s_sleep(1);
            }
        }
        if (fast) l1_inv();   // fresh L1 for this wave's h reads

        // h-part: 22 K-tiles; ring-buffer prefetch depth 8 of hi/lo A-frags
        const ushort_t* arow = Asrc + rowa * AH_ROW + q * 8;
        bf16x8 ra[8], rb[8];
#pragma unroll
        for (int p = 0; p < 8; ++p) {
            ra[p] = ld8(arow + p * 32);
            rb[p] = ld8(arow + HP + p * 32);
        }
#pragma unroll
        for (int kt = 0; kt < 22; ++kt) {
            bf16x8 ahi = ra[kt & 7];
            bf16x8 alo = rb[kt & 7];
            if (kt + 8 < 22) {
                ra[kt & 7] = ld8(arow + (kt + 8) * 32);
                rb[kt & 7] = ld8(arow + HP + (kt + 8) * 32);
            }
            int kb = 128 + kt * 32 + q * 8;
            bf16x8 bz8 = ld8(bsz + kb), br8 = ld8(bsr + kb), bh8 = ld8(bsh + kb);
            accz  = __builtin_amdgcn_mfma_f32_16x16x32_bf16(ahi, bz8, accz, 0, 0, 0);
            accr  = __builtin_amdgcn_mfma_f32_16x16x32_bf16(ahi, br8, accr, 0, 0, 0);
            accrh = __builtin_amdgcn_mfma_f32_16x16x32_bf16(ahi, bh8, accrh, 0, 0, 0);
            accz  = __builtin_amdgcn_mfma_f32_16x16x32_bf16(alo, bz8, accz, 0, 0, 0);
            accr  = __builtin_amdgcn_mfma_f32_16x16x32_bf16(alo, br8, accr, 0, 0, 0);
            accrh = __builtin_amdgcn_mfma_f32_16x16x32_bf16(alo, bh8, accrh, 0, 0, 0);
        }

        // epilogue: fast gates, update h, publish hi/lo
#pragma unroll
        for (int i = 0; i < 4; i++) {
            int rowc = g * 32 + rt * 16 + q * 4 + i;
            float z = fast_rcp(1.f + fast_exp(-(accz[i] + bzc)));
            float r = fast_rcp(1.f + fast_exp(-(accr[i] + brc)));
            float e2 = fast_exp(2.f * (accxh[i] + b0h + r * (accrh[i] + b1h)));
            float hh = 1.f - 2.f * fast_rcp(e2 + 1.f);
            float h = z * hown[i] + (1.f - z) * hh;
            if (j >= 700) h = 0.f;
            hown[i] = h;
            ushort_t hi = f2bf(h);
            Adst[rowc * AH_ROW + j] = hi;
            Adst[rowc * AH_ROW + HP + j] = f2bf(h - bf2f(hi));
        }

        // per-wave publish: drain own stores, then RMW flag (visible at once)
        if (fast) {
            wave_drain();
            if (lane == 0)
                __hip_atomic_fetch_add(myflag, 1, __ATOMIC_RELAXED, __HIP_MEMORY_SCOPE_AGENT);
        } else {
            if (lane == 0)
                __hip_atomic_store(myflag, t + 2, __ATOMIC_RELEASE, __HIP_MEMORY_SCOPE_AGENT);
            else
                __threadfence();
        }
    }

    // ---- final output -------------------------------------------------------
#pragma unroll
    for (int i = 0; i < 4; i++) {
        int rowc = g * 32 + rt * 16 + q * 4 + i;
        if (j >= 200 && j < 700)
            out[rowc * 500 + (j - 200)] = hown[i];
    }
}

extern "C" void kernel_launch(void* const* d_in, const int* in_sizes, int n_in,
                              void* d_out, int out_size, void* d_ws, size_t ws_size,
                              hipStream_t stream) {
    (void)in_sizes; (void)n_in; (void)out_size; (void)ws_size;
    const int*   enc  = (const int*)d_in[0];
    const float* lab  = (const float*)d_in[1];
    const float* emb  = (const float*)d_in[2];
    const float* W1   = (const float*)d_in[3];
    const float* b1   = (const float*)d_in[4];
    const float* Wx   = (const float*)d_in[5];
    float*       Wh   = (float*)d_in[6];
    const float* bias = (const float*)d_in[7];

    int*   cnt = (int*)d_ws;               // 5.2 KB of scratch used
    float* out = (float*)d_out;

    init_cnt<<<1, 1024, 0, stream>>>(cnt);

    hipFuncSetAttribute((const void*)gru_main,
                        hipFuncAttributeMaxDynamicSharedMemorySize, 96 * SB * 2);
    gru_main<<<NBLK, 256, 96 * SB * 2, stream>>>(enc, emb, Wx, Wh, lab, W1, b1,
                                                 bias, out, cnt);
}